// Round 5
// baseline (1995.057 us; speedup 1.0000x reference)
//
#include <hip/hip_runtime.h>
#include <math.h>

// Problem constants (B=16, T=64, NN=4096, H=1024)
constexpr int kB = 16;
constexpr int kT = 64;
constexpr int kH = 1024;

// ---------------------------------------------------------------------------
// 64x64-tile fp32 GEMM (decoder only; M=16 guard): C = X@W^T + bias
// ---------------------------------------------------------------------------
#define GBM 64
#define GBN 64
#define GBK 16
#define GPAD 4

__global__ __launch_bounds__(256)
void gemm_nt_bias(const float* __restrict__ X,   // [M,K]
                  const float* __restrict__ W,   // [N,K]
                  const float* __restrict__ bias,// [N]
                  float* __restrict__ C,         // [M,N]
                  int M, int N, int K)
{
    __shared__ float Xs[GBK][GBM + GPAD];
    __shared__ float Ws[GBK][GBN + GPAD];

    const int tid = threadIdx.x;
    const int bm = blockIdx.y * GBM;
    const int bn = blockIdx.x * GBN;
    const int tm = (tid >> 4) * 4;
    const int tn = (tid & 15) * 4;
    const int lr = tid >> 2;
    const int lc = (tid & 3) * 4;

    float acc[4][4] = {};

    for (int k0 = 0; k0 < K; k0 += GBK) {
        {
            const int gr = bm + lr;
            float4 v = make_float4(0.f, 0.f, 0.f, 0.f);
            if (gr < M) v = *(const float4*)(X + (long)gr * K + k0 + lc);
            Xs[lc + 0][lr] = v.x; Xs[lc + 1][lr] = v.y;
            Xs[lc + 2][lr] = v.z; Xs[lc + 3][lr] = v.w;
        }
        {
            const int gr = bn + lr;
            const float4 v = *(const float4*)(W + (long)gr * K + k0 + lc);
            Ws[lc + 0][lr] = v.x; Ws[lc + 1][lr] = v.y;
            Ws[lc + 2][lr] = v.z; Ws[lc + 3][lr] = v.w;
        }
        __syncthreads();

        #pragma unroll
        for (int k = 0; k < GBK; ++k) {
            const float4 a4 = *(const float4*)&Xs[k][tm];
            const float4 b4 = *(const float4*)&Ws[k][tn];
            acc[0][0] += a4.x * b4.x; acc[0][1] += a4.x * b4.y; acc[0][2] += a4.x * b4.z; acc[0][3] += a4.x * b4.w;
            acc[1][0] += a4.y * b4.x; acc[1][1] += a4.y * b4.y; acc[1][2] += a4.y * b4.z; acc[1][3] += a4.y * b4.w;
            acc[2][0] += a4.z * b4.x; acc[2][1] += a4.z * b4.y; acc[2][2] += a4.z * b4.z; acc[2][3] += a4.z * b4.w;
            acc[3][0] += a4.w * b4.x; acc[3][1] += a4.w * b4.y; acc[3][2] += a4.w * b4.z; acc[3][3] += a4.w * b4.w;
        }
        __syncthreads();
    }

    #pragma unroll
    for (int i = 0; i < 4; ++i) {
        const int gr = bm + tm + i;
        if (gr >= M) continue;
        #pragma unroll
        for (int jj = 0; jj < 4; ++jj) {
            const int gc = bn + tn + jj;
            C[(long)gr * N + gc] = acc[i][jj] + bias[gc];
        }
    }
}

// ---------------------------------------------------------------------------
// Phase-A GEMM: 64(M)x128(N) tile, 128 threads, 8x8 micro-tile, BK=16.
// 4 ds_read_b128 per 64 FMA (LDS/VALU ratio 1.5 vs 2.25 at 4x8).
// __launch_bounds__(128,3): VGPR cap ~170 -> no spill of the 64 accumulators
// (R3's gemm128 spilled: VGPR_Count=52 < 64 accs). Grid 24x16=384 blocks.
// Requires M%64==0, N%128==0, K%16==0.
// ---------------------------------------------------------------------------
__global__ __launch_bounds__(128, 3)
void gemm_a8(const float* __restrict__ X,   // [M,K]
             const float* __restrict__ W,   // [N,K]
             const float* __restrict__ bias,// [N]
             float* __restrict__ C,         // [M,N]
             int M, int N, int K)
{
    __shared__ float Xs[16][64 + 4];
    __shared__ float Ws[16][128 + 4];

    const int tid = threadIdx.x;      // 0..127
    const int bm = blockIdx.y * 64;
    const int bn = blockIdx.x * 128;
    const int tx = tid & 15;          // 0..15 col group
    const int ty = tid >> 4;          // 0..7  row group

    float acc[8][8] = {};

    for (int k0 = 0; k0 < K; k0 += 16) {
        // register prefetch: X 2 float4, W 4 float4 per thread
        float4 xv[2], wv[4];
        #pragma unroll
        for (int l = 0; l < 2; ++l) {
            const int idx = tid + 128 * l;          // 0..255
            xv[l] = *(const float4*)(X + (long)(bm + (idx >> 2)) * K + k0 + (idx & 3) * 4);
        }
        #pragma unroll
        for (int l = 0; l < 4; ++l) {
            const int idx = tid + 128 * l;          // 0..511
            wv[l] = *(const float4*)(W + (long)(bn + (idx >> 2)) * K + k0 + (idx & 3) * 4);
        }
        __syncthreads();   // previous tile's readers done
        #pragma unroll
        for (int l = 0; l < 2; ++l) {
            const int idx = tid + 128 * l;
            const int r = idx >> 2, c = (idx & 3) * 4;
            Xs[c + 0][r] = xv[l].x; Xs[c + 1][r] = xv[l].y;
            Xs[c + 2][r] = xv[l].z; Xs[c + 3][r] = xv[l].w;
        }
        #pragma unroll
        for (int l = 0; l < 4; ++l) {
            const int idx = tid + 128 * l;
            const int r = idx >> 2, c = (idx & 3) * 4;
            Ws[c + 0][r] = wv[l].x; Ws[c + 1][r] = wv[l].y;
            Ws[c + 2][r] = wv[l].z; Ws[c + 3][r] = wv[l].w;
        }
        __syncthreads();

        #pragma unroll
        for (int k = 0; k < 16; ++k) {
            const float4 a0 = *(const float4*)&Xs[k][4 * ty];
            const float4 a1 = *(const float4*)&Xs[k][32 + 4 * ty];
            const float4 b0 = *(const float4*)&Ws[k][4 * tx];
            const float4 b1 = *(const float4*)&Ws[k][64 + 4 * tx];
            const float a[8]  = {a0.x, a0.y, a0.z, a0.w, a1.x, a1.y, a1.z, a1.w};
            const float bb[8] = {b0.x, b0.y, b0.z, b0.w, b1.x, b1.y, b1.z, b1.w};
            #pragma unroll
            for (int i = 0; i < 8; ++i)
                #pragma unroll
                for (int j = 0; j < 8; ++j)
                    acc[i][j] += a[i] * bb[j];
        }
    }

    #pragma unroll
    for (int i = 0; i < 8; ++i) {
        const int row = bm + ((i < 4) ? (4 * ty + i) : (32 + 4 * ty + i - 4));
        #pragma unroll
        for (int jh = 0; jh < 2; ++jh) {
            const int col = bn + jh * 64 + 4 * tx;
            float4 v;
            v.x = acc[i][jh * 4 + 0] + bias[col + 0];
            v.y = acc[i][jh * 4 + 1] + bias[col + 1];
            v.z = acc[i][jh * 4 + 2] + bias[col + 2];
            v.w = acc[i][jh * 4 + 3] + bias[col + 3];
            *(float4*)(C + (long)row * N + col) = v;
        }
    }
}

// ---------------------------------------------------------------------------
// Fused pipelined GRU step: kernel k does layer0 step t=k (k<64) AND layer1
// step t=k-1 (k>0), computing gx1 on the fly (folds the phase-C GEMM).
// 256 blocks x 576 threads (9 waves), 1 block/CU (130 KB LDS).
// Waves: wid = 3*matsel + g; matsel 0: w_hh0 . h1_{k-1}   -> ghs[0]
//                            matsel 1: w_ih1 . h1_{k-1}   -> ghs[1] (gx1!)
//                            matsel 2: w_hh1 . h2_{k-2}   -> ghs[2]
// Each wave: R4-verified pattern — lane owns k-quads {4*lane+256*i}, 64
// register accumulators (4 jl x 16 b), 6-stage shfl butterfly, brev6 index.
// ---------------------------------------------------------------------------
__device__ __forceinline__ int brev6(int L) {
    return ((L & 1) << 5) | ((L & 2) << 3) | ((L & 4) << 1) |
           ((L & 8) >> 1) | ((L & 16) >> 3) | ((L & 32) >> 5);
}

__global__ __launch_bounds__(576)
void fused_step(const float* __restrict__ gx0_t,  // gx0 at t=k (guarded k<64)
                const float* __restrict__ w_hh0,
                const float* __restrict__ b_hh0,
                const float* __restrict__ w_ih1,
                const float* __restrict__ b_ih1,
                const float* __restrict__ w_hh1,
                const float* __restrict__ b_hh1,
                const float* __restrict__ h1prev, // h1_{k-1} rows, stride T*H
                float* __restrict__ h1out,        // h1_k rows, stride T*H
                const float* __restrict__ h2prev, // [16,1024]
                float* __restrict__ h2out,        // [16,1024]
                int k)
{
    __shared__ float hs[2][kB][kH];    // [0]=h1_{k-1}, [1]=h2_{k-2}; 128 KB
    __shared__ float ghs[3][3][64];    // [matsel][gate][jl*16+b]

    const int tid  = threadIdx.x;      // 0..575
    const int lane = tid & 63;
    const int wid  = tid >> 6;         // 0..8
    const int bx4  = blockIdx.x * 4;

    const int do_l0 = (k < kT);
    const int do_l1 = (k > 0);
    const int zeroA = (k == 0);
    const int zeroB = (k <= 1);

    // --- stage h1_{k-1} and h2_{k-2} into LDS: 8192 float4 over 576 thr ---
    for (int i = tid; i < 8192; i += 576) {
        const int buf = i >> 12;             // 0 or 1
        const int rem = i & 4095;
        const int b   = rem >> 8;            // 0..15
        const int q   = rem & 255;           // quad index
        float4 v = make_float4(0.f, 0.f, 0.f, 0.f);
        if (buf == 0) {
            if (!zeroA) v = *(const float4*)(h1prev + (long)b * (kT * kH) + q * 4);
        } else {
            if (!zeroB) v = *(const float4*)(h2prev + (long)b * kH + q * 4);
        }
        *(float4*)&hs[buf][b][q * 4] = v;
    }
    __syncthreads();

    // --- per-wave dot products ---
    {
        const int matsel = (wid >= 6) ? 2 : (wid >= 3 ? 1 : 0);
        const int g = wid - 3 * matsel;
        const float* Wm = (matsel == 0) ? w_hh0 : (matsel == 1) ? w_ih1 : w_hh1;
        const float* Bm = (matsel == 0) ? b_hh0 : (matsel == 1) ? b_ih1 : b_hh1;
        const float (*hsrc)[kH] = (matsel < 2) ? hs[0] : hs[1];

        float v[64];
        #pragma unroll
        for (int i = 0; i < 64; ++i) v[i] = 0.f;

        #pragma unroll
        for (int i = 0; i < 4; ++i) {
            const int kq = 4 * lane + 256 * i;
            float4 wv[4];
            #pragma unroll
            for (int jl = 0; jl < 4; ++jl)
                wv[jl] = *(const float4*)(Wm + ((long)g * kH + bx4 + jl) * kH + kq);
            #pragma unroll
            for (int b = 0; b < 16; ++b) {
                const float4 h4 = *(const float4*)&hsrc[b][kq];
                #pragma unroll
                for (int jl = 0; jl < 4; ++jl) {
                    v[jl * 16 + b] += wv[jl].x * h4.x + wv[jl].y * h4.y
                                    + wv[jl].z * h4.z + wv[jl].w * h4.w;
                }
            }
        }

        // butterfly reduce across 64 lanes
        int n = 64;
        #pragma unroll
        for (int s = 0; s < 6; ++s) {
            const int m = 1 << s;
            const int h = n >> 1;
            const bool up = (lane & m) != 0;
            #pragma unroll
            for (int i = 0; i < h; ++i) {
                const float send = up ? v[i] : v[i + h];
                const float recv = __shfl_xor(send, m, 64);
                v[i] = (up ? v[i + h] : v[i]) + recv;
            }
            n = h;
        }
        const int idx = brev6(lane);      // = jl*16 + b
        const int jl = idx >> 4;
        ghs[matsel][g][idx] = v[0] + Bm[(long)g * kH + bx4 + jl];
    }
    __syncthreads();

    // --- layer0 cell update (wave 0) ---
    if (tid < 64 && do_l0) {
        const int pb = lane & 15;
        const int pj = lane >> 4;
        const int jg = bx4 + pj;
        const float* gxrow = gx0_t + (long)pb * (kT * 3 * kH);
        const float xr = gxrow[jg];
        const float xz = gxrow[kH + jg];
        const float xn = gxrow[2 * kH + jg];
        const float hr = ghs[0][0][pj * 16 + pb];
        const float hz = ghs[0][1][pj * 16 + pb];
        const float hn = ghs[0][2][pj * 16 + pb];
        const float hp = hs[0][pb][jg];
        const float r = 1.f / (1.f + __expf(-(xr + hr)));
        const float z = 1.f / (1.f + __expf(-(xz + hz)));
        const float nn = tanhf(xn + r * hn);
        h1out[(long)pb * (kT * kH) + jg] = (1.f - z) * nn + z * hp;
    }

    // --- layer1 cell update (wave 1): gx1 = ghs[1] (includes b_ih1) ---
    if (tid >= 64 && tid < 128 && do_l1) {
        const int pb = lane & 15;
        const int pj = lane >> 4;
        const int jg = bx4 + pj;
        const float xr = ghs[1][0][pj * 16 + pb];
        const float xz = ghs[1][1][pj * 16 + pb];
        const float xn = ghs[1][2][pj * 16 + pb];
        const float hr = ghs[2][0][pj * 16 + pb];
        const float hz = ghs[2][1][pj * 16 + pb];
        const float hn = ghs[2][2][pj * 16 + pb];
        const float hp = hs[1][pb][jg];
        const float r = 1.f / (1.f + __expf(-(xr + hr)));
        const float z = 1.f / (1.f + __expf(-(xz + hz)));
        const float nn = tanhf(xn + r * hn);
        h2out[(long)pb * kH + jg] = (1.f - z) * nn + z * hp;
    }
}

// ---------------------------------------------------------------------------
// kernel_launch
// ---------------------------------------------------------------------------
extern "C" void kernel_launch(void* const* d_in, const int* in_sizes, int n_in,
                              void* d_out, int out_size, void* d_ws, size_t ws_size,
                              hipStream_t stream)
{
    const float* x        = (const float*)d_in[0];   // [16,64,4096]
    const float* w_ih_l0  = (const float*)d_in[1];   // [3072,4096]
    const float* w_hh_l0  = (const float*)d_in[2];   // [3072,1024]
    const float* b_ih_l0  = (const float*)d_in[3];   // [3072]
    const float* b_hh_l0  = (const float*)d_in[4];   // [3072]
    const float* w_ih_l1  = (const float*)d_in[5];   // [3072,1024]
    const float* w_hh_l1  = (const float*)d_in[6];   // [3072,1024]
    const float* b_ih_l1  = (const float*)d_in[7];   // [3072]
    const float* b_hh_l1  = (const float*)d_in[8];   // [3072]
    const float* dec_w    = (const float*)d_in[9];   // [4096,1024]
    const float* dec_b    = (const float*)d_in[10];  // [4096]
    float* out = (float*)d_out;                      // [16,4096]

    // Workspace (floats)
    float* ws   = (float*)d_ws;
    float* gx0  = ws;                                   // [16*64, 3072] b-major rows
    float* h1   = gx0 + (size_t)1024 * 3072;            // [16*64, 1024] b-major rows
    float* bufA = h1 + (size_t)1024 * 1024;             // [16, 1024]
    float* bufB = bufA + (size_t)kB * kH;               // [16, 1024]

    // Phase A: gx0 = x @ w_ih_l0^T + b_ih_l0   (M=1024, N=3072, K=4096)
    gemm_a8<<<dim3(3072 / 128, 1024 / 64), 128, 0, stream>>>(
        x, w_ih_l0, b_ih_l0, gx0, 1024, 3072, 4096);

    // Pipelined fused recurrence: 65 launches cover layer0 t=0..63 and
    // layer1 t=0..63 (kernel k: layer0 t=k, layer1 t=k-1; gx1 computed
    // in-kernel from h1_{k-1} — no separate phase-C GEMM).
    for (int k = 0; k <= kT; ++k) {
        const float* gx0_t  = gx0 + (size_t)(k < kT ? k : 0) * 3 * kH;
        const float* h1prev = (k > 0) ? (h1 + (size_t)(k - 1) * kH) : h1;
        float* h1out        = h1 + (size_t)(k < kT ? k : 0) * kH;
        // h2_{t-1} (t=k-1) lives in parity (k-2)&1 == k&1; output parity (k-1)&1
        const float* h2prev = (k & 1) ? bufA : bufB;
        float* h2out        = ((k - 1) & 1) ? bufA : bufB;
        fused_step<<<256, 576, 0, stream>>>(
            gx0_t, w_hh_l0, b_hh_l0, w_ih_l1, b_ih_l1, w_hh_l1, b_hh_l1,
            h1prev, h1out, h2prev, h2out, k);
    }

    // Final h2 (t=63, odd) is in bufA.
    // Decoder: out = h2_last @ dec_w^T + dec_b   (M=16, N=4096, K=1024)
    gemm_nt_bias<<<dim3(4096 / GBN, 1), 256, 0, stream>>>(
        bufA, dec_w, dec_b, out, kB, 4096, 1024);
}

// Round 6
// 1591.934 us; speedup vs baseline: 1.2532x; 1.2532x over previous
//
#include <hip/hip_runtime.h>
#include <math.h>

// Problem constants (B=16, T=64, NN=4096, H=1024)
constexpr int kB = 16;
constexpr int kT = 64;
constexpr int kH = 1024;

// ---------------------------------------------------------------------------
// 64x64-tile fp32 GEMM (decoder only; M=16 guard): C = X@W^T + bias
// ---------------------------------------------------------------------------
#define GBM 64
#define GBN 64
#define GBK 16
#define GPAD 4

__global__ __launch_bounds__(256)
void gemm_nt_bias(const float* __restrict__ X,   // [M,K]
                  const float* __restrict__ W,   // [N,K]
                  const float* __restrict__ bias,// [N]
                  float* __restrict__ C,         // [M,N]
                  int M, int N, int K)
{
    __shared__ float Xs[GBK][GBM + GPAD];
    __shared__ float Ws[GBK][GBN + GPAD];

    const int tid = threadIdx.x;
    const int bm = blockIdx.y * GBM;
    const int bn = blockIdx.x * GBN;
    const int tm = (tid >> 4) * 4;
    const int tn = (tid & 15) * 4;
    const int lr = tid >> 2;
    const int lc = (tid & 3) * 4;

    float acc[4][4] = {};

    for (int k0 = 0; k0 < K; k0 += GBK) {
        {
            const int gr = bm + lr;
            float4 v = make_float4(0.f, 0.f, 0.f, 0.f);
            if (gr < M) v = *(const float4*)(X + (long)gr * K + k0 + lc);
            Xs[lc + 0][lr] = v.x; Xs[lc + 1][lr] = v.y;
            Xs[lc + 2][lr] = v.z; Xs[lc + 3][lr] = v.w;
        }
        {
            const int gr = bn + lr;
            const float4 v = *(const float4*)(W + (long)gr * K + k0 + lc);
            Ws[lc + 0][lr] = v.x; Ws[lc + 1][lr] = v.y;
            Ws[lc + 2][lr] = v.z; Ws[lc + 3][lr] = v.w;
        }
        __syncthreads();

        #pragma unroll
        for (int k = 0; k < GBK; ++k) {
            const float4 a4 = *(const float4*)&Xs[k][tm];
            const float4 b4 = *(const float4*)&Ws[k][tn];
            acc[0][0] += a4.x * b4.x; acc[0][1] += a4.x * b4.y; acc[0][2] += a4.x * b4.z; acc[0][3] += a4.x * b4.w;
            acc[1][0] += a4.y * b4.x; acc[1][1] += a4.y * b4.y; acc[1][2] += a4.y * b4.z; acc[1][3] += a4.y * b4.w;
            acc[2][0] += a4.z * b4.x; acc[2][1] += a4.z * b4.y; acc[2][2] += a4.z * b4.z; acc[2][3] += a4.z * b4.w;
            acc[3][0] += a4.w * b4.x; acc[3][1] += a4.w * b4.y; acc[3][2] += a4.w * b4.z; acc[3][3] += a4.w * b4.w;
        }
        __syncthreads();
    }

    #pragma unroll
    for (int i = 0; i < 4; ++i) {
        const int gr = bm + tm + i;
        if (gr >= M) continue;
        #pragma unroll
        for (int jj = 0; jj < 4; ++jj) {
            const int gc = bn + tn + jj;
            C[(long)gr * N + gc] = acc[i][jj] + bias[gc];
        }
    }
}

// ---------------------------------------------------------------------------
// Phase-A GEMM: R4's verified 64(M)x128(N) tile, 4x8 micro, 256 threads.
// Measured: 513 us, VGPR 40 (no spill), 0 bank conflicts. Do not re-fatten
// the micro-tile: 8x8 at 128 thr spilled (R5, VGPR_Count=72, +18MB scratch).
// ---------------------------------------------------------------------------
__global__ __launch_bounds__(256)
void gemm_a(const float* __restrict__ X,   // [M,K]
            const float* __restrict__ W,   // [N,K]
            const float* __restrict__ bias,// [N]
            float* __restrict__ C,         // [M,N]
            int M, int N, int K)
{
    __shared__ float Xs[8][64 + 4];
    __shared__ float Ws[8][128 + 4];

    const int tid = threadIdx.x;
    const int bm = blockIdx.y * 64;
    const int bn = blockIdx.x * 128;
    const int tx = tid & 15;          // 0..15 col group
    const int ty = tid >> 4;          // 0..15 row group
    const int xr = tid >> 1;          // X loader row (threads 0..127)
    const int wr = tid >> 1;          // W loader row 0..127
    const int lk = (tid & 1) * 4;     // loader k {0,4}

    float acc[4][8] = {};

    for (int k0 = 0; k0 < K; k0 += 8) {
        float4 xv = make_float4(0.f, 0.f, 0.f, 0.f);
        if (tid < 128) xv = *(const float4*)(X + (long)(bm + xr) * K + k0 + lk);
        const float4 wv = *(const float4*)(W + (long)(bn + wr) * K + k0 + lk);
        __syncthreads();   // previous tile's readers done
        if (tid < 128) {
            Xs[lk + 0][xr] = xv.x; Xs[lk + 1][xr] = xv.y;
            Xs[lk + 2][xr] = xv.z; Xs[lk + 3][xr] = xv.w;
        }
        Ws[lk + 0][wr] = wv.x; Ws[lk + 1][wr] = wv.y;
        Ws[lk + 2][wr] = wv.z; Ws[lk + 3][wr] = wv.w;
        __syncthreads();

        #pragma unroll
        for (int k = 0; k < 8; ++k) {
            const float4 a4 = *(const float4*)&Xs[k][4 * ty];
            const float4 b0 = *(const float4*)&Ws[k][4 * tx];
            const float4 b1 = *(const float4*)&Ws[k][64 + 4 * tx];
            const float a[4] = {a4.x, a4.y, a4.z, a4.w};
            const float bb[8] = {b0.x, b0.y, b0.z, b0.w, b1.x, b1.y, b1.z, b1.w};
            #pragma unroll
            for (int i = 0; i < 4; ++i)
                #pragma unroll
                for (int j = 0; j < 8; ++j)
                    acc[i][j] += a[i] * bb[j];
        }
    }

    #pragma unroll
    for (int i = 0; i < 4; ++i) {
        const int row = bm + 4 * ty + i;
        #pragma unroll
        for (int jh = 0; jh < 2; ++jh) {
            const int col = bn + jh * 64 + 4 * tx;
            float4 v;
            v.x = acc[i][jh * 4 + 0] + bias[col + 0];
            v.y = acc[i][jh * 4 + 1] + bias[col + 1];
            v.z = acc[i][jh * 4 + 2] + bias[col + 2];
            v.w = acc[i][jh * 4 + 3] + bias[col + 3];
            *(float4*)(C + (long)row * N + col) = v;
        }
    }
}

// ---------------------------------------------------------------------------
// Weight pack: fp32 -> bf16 (RNE), float4 -> ushort4. Halves per-step weight
// bytes AND brings the fused step's per-XCD weight footprint 4.6 -> 2.3 MB,
// back under the 4 MB XCD L2 (the R5 regression's root cause).
// ---------------------------------------------------------------------------
__device__ __forceinline__ unsigned short f2bf(float f) {
    unsigned u = __float_as_uint(f);
    u = u + 0x7FFFu + ((u >> 16) & 1u);     // round-to-nearest-even
    return (unsigned short)(u >> 16);
}

__global__ __launch_bounds__(256)
void pack_bf16(const float* __restrict__ src, unsigned short* __restrict__ dst,
               int n4)   // n4 = element count / 4
{
    const int i = blockIdx.x * 256 + threadIdx.x;
    if (i < n4) {
        const float4 v = ((const float4*)src)[i];
        ushort4 o;
        o.x = f2bf(v.x); o.y = f2bf(v.y); o.z = f2bf(v.z); o.w = f2bf(v.w);
        ((ushort4*)dst)[i] = o;
    }
}

// ---------------------------------------------------------------------------
// Fused pipelined GRU step (R5 structure, bf16 weights). Kernel k does
// layer0 t=k (k<64) AND layer1 t=k-1 (k>0); gx1 computed on the fly.
// 256 blocks x 576 threads (9 waves). h stays fp32 in LDS (dense 4-float
// lane stride, optimal ds_read_b128 pattern); weights arrive as 8B dwordx2
// (4 bf16) per (i,jl), unpacked with one shift/and each (~6% extra VALU).
// Accumulation fp32. Only weights are quantized.
// ---------------------------------------------------------------------------
__device__ __forceinline__ int brev6(int L) {
    return ((L & 1) << 5) | ((L & 2) << 3) | ((L & 4) << 1) |
           ((L & 8) >> 1) | ((L & 16) >> 3) | ((L & 32) >> 5);
}

__global__ __launch_bounds__(576)
void fused_step(const float* __restrict__ gx0_t,   // gx0 at t=k (guarded k<64)
                const unsigned short* __restrict__ w_hh0, // bf16 [3H][H]
                const float* __restrict__ b_hh0,
                const unsigned short* __restrict__ w_ih1, // bf16 [3H][H]
                const float* __restrict__ b_ih1,
                const unsigned short* __restrict__ w_hh1, // bf16 [3H][H]
                const float* __restrict__ b_hh1,
                const float* __restrict__ h1prev,  // h1_{k-1} rows, stride T*H
                float* __restrict__ h1out,         // h1_k rows, stride T*H
                const float* __restrict__ h2prev,  // [16,1024]
                float* __restrict__ h2out,         // [16,1024]
                int k)
{
    __shared__ float hs[2][kB][kH];    // [0]=h1_{k-1}, [1]=h2_{k-2}; 128 KB
    __shared__ float ghs[3][3][64];    // [matsel][gate][jl*16+b]

    const int tid  = threadIdx.x;      // 0..575
    const int lane = tid & 63;
    const int wid  = tid >> 6;         // 0..8
    const int bx4  = blockIdx.x * 4;

    const int do_l0 = (k < kT);
    const int do_l1 = (k > 0);
    const int zeroA = (k == 0);
    const int zeroB = (k <= 1);

    // --- stage h1_{k-1} and h2_{k-2} into LDS: 8192 float4 over 576 thr ---
    for (int i = tid; i < 8192; i += 576) {
        const int buf = i >> 12;             // 0 or 1
        const int rem = i & 4095;
        const int b   = rem >> 8;            // 0..15
        const int q   = rem & 255;           // quad index
        float4 v = make_float4(0.f, 0.f, 0.f, 0.f);
        if (buf == 0) {
            if (!zeroA) v = *(const float4*)(h1prev + (long)b * (kT * kH) + q * 4);
        } else {
            if (!zeroB) v = *(const float4*)(h2prev + (long)b * kH + q * 4);
        }
        *(float4*)&hs[buf][b][q * 4] = v;
    }
    __syncthreads();

    // --- per-wave dot products ---
    {
        const int matsel = (wid >= 6) ? 2 : (wid >= 3 ? 1 : 0);
        const int g = wid - 3 * matsel;
        const unsigned short* Wm = (matsel == 0) ? w_hh0
                                 : (matsel == 1) ? w_ih1 : w_hh1;
        const float* Bm = (matsel == 0) ? b_hh0 : (matsel == 1) ? b_ih1 : b_hh1;
        const float (*hsrc)[kH] = (matsel < 2) ? hs[0] : hs[1];

        float v[64];
        #pragma unroll
        for (int i = 0; i < 64; ++i) v[i] = 0.f;

        #pragma unroll
        for (int i = 0; i < 4; ++i) {
            const int kq = 4 * lane + 256 * i;
            float4 wv[4];
            #pragma unroll
            for (int jl = 0; jl < 4; ++jl) {
                const uint2 p = *(const uint2*)(Wm + ((long)g * kH + bx4 + jl) * kH + kq);
                wv[jl].x = __uint_as_float(p.x << 16);
                wv[jl].y = __uint_as_float(p.x & 0xFFFF0000u);
                wv[jl].z = __uint_as_float(p.y << 16);
                wv[jl].w = __uint_as_float(p.y & 0xFFFF0000u);
            }
            #pragma unroll
            for (int b = 0; b < 16; ++b) {
                const float4 h4 = *(const float4*)&hsrc[b][kq];
                #pragma unroll
                for (int jl = 0; jl < 4; ++jl) {
                    v[jl * 16 + b] += wv[jl].x * h4.x + wv[jl].y * h4.y
                                    + wv[jl].z * h4.z + wv[jl].w * h4.w;
                }
            }
        }

        // butterfly reduce across 64 lanes
        int n = 64;
        #pragma unroll
        for (int s = 0; s < 6; ++s) {
            const int m = 1 << s;
            const int h = n >> 1;
            const bool up = (lane & m) != 0;
            #pragma unroll
            for (int i = 0; i < h; ++i) {
                const float send = up ? v[i] : v[i + h];
                const float recv = __shfl_xor(send, m, 64);
                v[i] = (up ? v[i + h] : v[i]) + recv;
            }
            n = h;
        }
        const int idx = brev6(lane);      // = jl*16 + b
        const int jl = idx >> 4;
        ghs[matsel][g][idx] = v[0] + Bm[(long)g * kH + bx4 + jl];
    }
    __syncthreads();

    // --- layer0 cell update (wave 0) ---
    if (tid < 64 && do_l0) {
        const int pb = lane & 15;
        const int pj = lane >> 4;
        const int jg = bx4 + pj;
        const float* gxrow = gx0_t + (long)pb * (kT * 3 * kH);
        const float xr = gxrow[jg];
        const float xz = gxrow[kH + jg];
        const float xn = gxrow[2 * kH + jg];
        const float hr = ghs[0][0][pj * 16 + pb];
        const float hz = ghs[0][1][pj * 16 + pb];
        const float hn = ghs[0][2][pj * 16 + pb];
        const float hp = hs[0][pb][jg];
        const float r = 1.f / (1.f + __expf(-(xr + hr)));
        const float z = 1.f / (1.f + __expf(-(xz + hz)));
        const float nn = tanhf(xn + r * hn);
        h1out[(long)pb * (kT * kH) + jg] = (1.f - z) * nn + z * hp;
    }

    // --- layer1 cell update (wave 1): gx1 = ghs[1] (includes b_ih1) ---
    if (tid >= 64 && tid < 128 && do_l1) {
        const int pb = lane & 15;
        const int pj = lane >> 4;
        const int jg = bx4 + pj;
        const float xr = ghs[1][0][pj * 16 + pb];
        const float xz = ghs[1][1][pj * 16 + pb];
        const float xn = ghs[1][2][pj * 16 + pb];
        const float hr = ghs[2][0][pj * 16 + pb];
        const float hz = ghs[2][1][pj * 16 + pb];
        const float hn = ghs[2][2][pj * 16 + pb];
        const float hp = hs[1][pb][jg];
        const float r = 1.f / (1.f + __expf(-(xr + hr)));
        const float z = 1.f / (1.f + __expf(-(xz + hz)));
        const float nn = tanhf(xn + r * hn);
        h2out[(long)pb * kH + jg] = (1.f - z) * nn + z * hp;
    }
}

// ---------------------------------------------------------------------------
// kernel_launch
// ---------------------------------------------------------------------------
extern "C" void kernel_launch(void* const* d_in, const int* in_sizes, int n_in,
                              void* d_out, int out_size, void* d_ws, size_t ws_size,
                              hipStream_t stream)
{
    const float* x        = (const float*)d_in[0];   // [16,64,4096]
    const float* w_ih_l0  = (const float*)d_in[1];   // [3072,4096]
    const float* w_hh_l0  = (const float*)d_in[2];   // [3072,1024]
    const float* b_ih_l0  = (const float*)d_in[3];   // [3072]
    const float* b_hh_l0  = (const float*)d_in[4];   // [3072]
    const float* w_ih_l1  = (const float*)d_in[5];   // [3072,1024]
    const float* w_hh_l1  = (const float*)d_in[6];   // [3072,1024]
    const float* b_ih_l1  = (const float*)d_in[7];   // [3072]
    const float* b_hh_l1  = (const float*)d_in[8];   // [3072]
    const float* dec_w    = (const float*)d_in[9];   // [4096,1024]
    const float* dec_b    = (const float*)d_in[10];  // [4096]
    float* out = (float*)d_out;                      // [16,4096]

    // Workspace (floats/shorts). Total ~35.3 MB.
    float* ws   = (float*)d_ws;
    float* gx0  = ws;                                   // [16*64, 3072] fp32, 12 MB
    float* h1   = gx0 + (size_t)1024 * 3072;            // [16*64, 1024] fp32, 4 MB
    float* bufA = h1 + (size_t)1024 * 1024;             // [16, 1024]
    float* bufB = bufA + (size_t)kB * kH;               // [16, 1024]
    unsigned short* wbf0 = (unsigned short*)(bufB + (size_t)kB * kH); // 3x6MB bf16
    unsigned short* wbf1 = wbf0 + (size_t)3 * kH * kH;
    unsigned short* wbf2 = wbf1 + (size_t)3 * kH * kH;

    const int wn4 = 3 * kH * kH / 4;                    // 786432 float4s / matrix

    // Pack recurrence weights fp32 -> bf16 (runs every call; ~15 us total)
    pack_bf16<<<(wn4 + 255) / 256, 256, 0, stream>>>(w_hh_l0, wbf0, wn4);
    pack_bf16<<<(wn4 + 255) / 256, 256, 0, stream>>>(w_ih_l1, wbf1, wn4);
    pack_bf16<<<(wn4 + 255) / 256, 256, 0, stream>>>(w_hh_l1, wbf2, wn4);

    // Phase A: gx0 = x @ w_ih_l0^T + b_ih_l0   (M=1024, N=3072, K=4096)
    gemm_a<<<dim3(3072 / 128, 1024 / 64), 256, 0, stream>>>(
        x, w_ih_l0, b_ih_l0, gx0, 1024, 3072, 4096);

    // Pipelined fused recurrence: 65 launches (kernel k: layer0 t=k,
    // layer1 t=k-1; gx1 computed in-kernel — no separate phase-C GEMM).
    for (int k = 0; k <= kT; ++k) {
        const float* gx0_t  = gx0 + (size_t)(k < kT ? k : 0) * 3 * kH;
        const float* h1prev = (k > 0) ? (h1 + (size_t)(k - 1) * kH) : h1;
        float* h1out        = h1 + (size_t)(k < kT ? k : 0) * kH;
        const float* h2prev = (k & 1) ? bufA : bufB;
        float* h2out        = ((k - 1) & 1) ? bufA : bufB;
        fused_step<<<256, 576, 0, stream>>>(
            gx0_t, wbf0, b_hh_l0, wbf1, b_ih_l1, wbf2, b_hh_l1,
            h1prev, h1out, h2prev, h2out, k);
    }

    // Final h2 (t=63, odd) is in bufA.
    // Decoder: out = h2_last @ dec_w^T + dec_b   (M=16, N=4096, K=1024)
    gemm_nt_bias<<<dim3(4096 / GBN, 1), 256, 0, stream>>>(
        bufA, dec_w, dec_b, out, kB, 4096, 1024);
}

// Round 7
// 1172.803 us; speedup vs baseline: 1.7011x; 1.3574x over previous
//
#include <hip/hip_runtime.h>
#include <math.h>

// Problem constants (B=16, T=64, NN=4096, H=1024)
constexpr int kB = 16;
constexpr int kT = 64;
constexpr int kH = 1024;

typedef short bf16x8 __attribute__((ext_vector_type(8)));   // 8 bf16 = 4 VGPR
typedef float floatx4 __attribute__((ext_vector_type(4)));  // MFMA acc

// ---------------------------------------------------------------------------
// bf16 convert helpers. f2bf_rne: exact round-nearest-even (pack kernel).
// f2bf_fast: round-half-away (2 ops) for in-kernel staging — bias negligible
// vs bf16's 2^-9 quantization.
// ---------------------------------------------------------------------------
__device__ __forceinline__ unsigned short f2bf_rne(float f) {
    unsigned u = __float_as_uint(f);
    u = u + 0x7FFFu + ((u >> 16) & 1u);
    return (unsigned short)(u >> 16);
}
__device__ __forceinline__ unsigned f2bf_fast_u(float f) {
    return (__float_as_uint(f) + 0x8000u) >> 16;
}
__device__ __forceinline__ uint4 pack8(const float4 a, const float4 b) {
    uint4 r;
    r.x = f2bf_fast_u(a.x) | (f2bf_fast_u(a.y) << 16);
    r.y = f2bf_fast_u(a.z) | (f2bf_fast_u(a.w) << 16);
    r.z = f2bf_fast_u(b.x) | (f2bf_fast_u(b.y) << 16);
    r.w = f2bf_fast_u(b.z) | (f2bf_fast_u(b.w) << 16);
    return r;
}

__global__ __launch_bounds__(256)
void pack_bf16(const float* __restrict__ src, unsigned short* __restrict__ dst,
               int n4)
{
    const int i = blockIdx.x * 256 + threadIdx.x;
    if (i < n4) {
        const float4 v = ((const float4*)src)[i];
        ushort4 o;
        o.x = f2bf_rne(v.x); o.y = f2bf_rne(v.y);
        o.z = f2bf_rne(v.z); o.w = f2bf_rne(v.w);
        ((ushort4*)dst)[i] = o;
    }
}

// ---------------------------------------------------------------------------
// 64x64-tile fp32 GEMM (decoder only; M=16 guard): C = X@W^T + bias
// ---------------------------------------------------------------------------
#define GBM 64
#define GBN 64
#define GBK 16
#define GPAD 4

__global__ __launch_bounds__(256)
void gemm_nt_bias(const float* __restrict__ X, const float* __restrict__ W,
                  const float* __restrict__ bias, float* __restrict__ C,
                  int M, int N, int K)
{
    __shared__ float Xs[GBK][GBM + GPAD];
    __shared__ float Ws[GBK][GBN + GPAD];

    const int tid = threadIdx.x;
    const int bm = blockIdx.y * GBM;
    const int bn = blockIdx.x * GBN;
    const int tm = (tid >> 4) * 4;
    const int tn = (tid & 15) * 4;
    const int lr = tid >> 2;
    const int lc = (tid & 3) * 4;

    float acc[4][4] = {};

    for (int k0 = 0; k0 < K; k0 += GBK) {
        {
            const int gr = bm + lr;
            float4 v = make_float4(0.f, 0.f, 0.f, 0.f);
            if (gr < M) v = *(const float4*)(X + (long)gr * K + k0 + lc);
            Xs[lc + 0][lr] = v.x; Xs[lc + 1][lr] = v.y;
            Xs[lc + 2][lr] = v.z; Xs[lc + 3][lr] = v.w;
        }
        {
            const int gr = bn + lr;
            const float4 v = *(const float4*)(W + (long)gr * K + k0 + lc);
            Ws[lc + 0][lr] = v.x; Ws[lc + 1][lr] = v.y;
            Ws[lc + 2][lr] = v.z; Ws[lc + 3][lr] = v.w;
        }
        __syncthreads();
        #pragma unroll
        for (int k = 0; k < GBK; ++k) {
            const float4 a4 = *(const float4*)&Xs[k][tm];
            const float4 b4 = *(const float4*)&Ws[k][tn];
            acc[0][0] += a4.x * b4.x; acc[0][1] += a4.x * b4.y; acc[0][2] += a4.x * b4.z; acc[0][3] += a4.x * b4.w;
            acc[1][0] += a4.y * b4.x; acc[1][1] += a4.y * b4.y; acc[1][2] += a4.y * b4.z; acc[1][3] += a4.y * b4.w;
            acc[2][0] += a4.z * b4.x; acc[2][1] += a4.z * b4.y; acc[2][2] += a4.z * b4.z; acc[2][3] += a4.z * b4.w;
            acc[3][0] += a4.w * b4.x; acc[3][1] += a4.w * b4.y; acc[3][2] += a4.w * b4.z; acc[3][3] += a4.w * b4.w;
        }
        __syncthreads();
    }

    #pragma unroll
    for (int i = 0; i < 4; ++i) {
        const int gr = bm + tm + i;
        if (gr >= M) continue;
        #pragma unroll
        for (int jj = 0; jj < 4; ++jj) {
            const int gc = bn + tn + jj;
            C[(long)gr * N + gc] = acc[i][jj] + bias[gc];
        }
    }
}

// ---------------------------------------------------------------------------
// Phase-A MFMA GEMM: C[M,N] = X[M,K] @ W[N,K]^T + bias, fp32 in / fp32 out,
// bf16 internally (converted during LDS staging — no packed copies in ws).
// Tile 64(M)x128(N), BK=32, 256 thr = 4 waves; wave quadrant 32x64 =
// 2x4 MFMA(16x16x32) tiles. LDS rows padded to 40 bf16 (80 B = 20 dwords,
// 2-way bank alias on frag reads = free). Grid (24,16) = 384 blocks.
// MFMA layouts (m89-verified): A[m=lane&15][k=(lane>>4)*8+j],
// B[n=lane&15][k=...], D[row=(lane>>4)*4+reg][col=lane&15].
// ---------------------------------------------------------------------------
__global__ __launch_bounds__(256)
void gemm_mfma_a(const float* __restrict__ X,   // [M,K]
                 const float* __restrict__ W,   // [N,K]
                 const float* __restrict__ bias,// [N]
                 float* __restrict__ C,         // [M,N]
                 int M, int N, int K)
{
    __shared__ __attribute__((aligned(16))) unsigned short As[64 * 40];
    __shared__ __attribute__((aligned(16))) unsigned short Bs[128 * 40];

    const int tid  = threadIdx.x;
    const int lane = tid & 63;
    const int w    = tid >> 6;
    const int qm   = w & 1;            // 0..1 (32-row half)
    const int qn   = w >> 1;           // 0..1 (64-col half)
    const int bm   = blockIdx.y * 64;
    const int bn   = blockIdx.x * 128;
    const int al   = lane & 15;
    const int aq   = lane >> 4;

    floatx4 acc[2][4];
    #pragma unroll
    for (int i = 0; i < 2; ++i)
        #pragma unroll
        for (int j = 0; j < 4; ++j)
            acc[i][j] = (floatx4){0.f, 0.f, 0.f, 0.f};

    // loader indices
    const int ar = tid >> 2;           // A row 0..63
    const int ak = (tid & 3) * 8;      // A k-offset {0,8,16,24}

    for (int k0 = 0; k0 < K; k0 += 32) {
        // ---- load to registers (fp32), convert later ----
        const float* ap = X + (long)(bm + ar) * K + k0 + ak;
        const float4 av0 = *(const float4*)(ap);
        const float4 av1 = *(const float4*)(ap + 4);
        float4 bv0[2], bv1[2];
        #pragma unroll
        for (int l = 0; l < 2; ++l) {
            const int c = tid + 256 * l;        // 0..511
            const float* bp = W + (long)(bn + (c >> 2)) * K + k0 + (c & 3) * 8;
            bv0[l] = *(const float4*)(bp);
            bv1[l] = *(const float4*)(bp + 4);
        }
        __syncthreads();   // previous tile's readers done
        *(uint4*)&As[ar * 40 + ak] = pack8(av0, av1);
        #pragma unroll
        for (int l = 0; l < 2; ++l) {
            const int c = tid + 256 * l;
            *(uint4*)&Bs[(c >> 2) * 40 + (c & 3) * 8] = pack8(bv0[l], bv1[l]);
        }
        __syncthreads();

        // ---- fragments + 8 MFMAs ----
        bf16x8 a[2], b[4];
        #pragma unroll
        for (int i = 0; i < 2; ++i)
            a[i] = *(const bf16x8*)&As[(qm * 32 + i * 16 + al) * 40 + aq * 8];
        #pragma unroll
        for (int j = 0; j < 4; ++j)
            b[j] = *(const bf16x8*)&Bs[(qn * 64 + j * 16 + al) * 40 + aq * 8];
        #pragma unroll
        for (int i = 0; i < 2; ++i)
            #pragma unroll
            for (int j = 0; j < 4; ++j)
                acc[i][j] = __builtin_amdgcn_mfma_f32_16x16x32_bf16(
                    a[i], b[j], acc[i][j], 0, 0, 0);
    }

    // ---- epilogue: D[row=(aq*4+r)][col=al] per 16x16 tile ----
    #pragma unroll
    for (int i = 0; i < 2; ++i) {
        #pragma unroll
        for (int j = 0; j < 4; ++j) {
            const int row0 = bm + qm * 32 + i * 16 + aq * 4;
            const int col  = bn + qn * 64 + j * 16 + al;
            const float bv = bias[col];
            #pragma unroll
            for (int r = 0; r < 4; ++r)
                C[(long)(row0 + r) * N + col] = acc[i][j][r] + bv;
        }
    }
}

// ---------------------------------------------------------------------------
// Fused pipelined GRU step, MFMA edition. Kernel k: layer0 t=k (k<64) and
// layer1 t=k-1 (k>0); gx1 computed on the fly. Grid 64 blocks x 768 thr
// (12 waves); block owns j-columns [16*bx, 16*bx+16).
// Wave (m = wid>>2, kh = wid&3): matrix m (0: w_hh0, 1: w_ih1, 2: w_hh1),
// K-quarter kh*256. Per wave: 8 k-steps x 3 gates MFMA(16x16x32):
//   A = h (bf16, LDS; row pad +8 -> lane stride 516 dwords = 2-way = free)
//   B = weight rows from global (uint4/lane; wave covers 16 full lines)
//   D[b=(lane>>4)*4+reg][j=lane&15] -> partials in LDS, summed over kh in
// the update phase. h_prev for the z*h recursion read fp32 from global
// (quantization stays inside dots only — non-recursive error).
// ---------------------------------------------------------------------------
__global__ __launch_bounds__(768)
void fused_mfma_step(const float* __restrict__ gx0_t,
                     const unsigned short* __restrict__ w0, const float* __restrict__ bb0,
                     const unsigned short* __restrict__ w1, const float* __restrict__ bb1,
                     const unsigned short* __restrict__ w2, const float* __restrict__ bb2,
                     const float* __restrict__ h1prev, float* __restrict__ h1out,
                     const float* __restrict__ h2prev, float* __restrict__ h2out,
                     int k)
{
    __shared__ __attribute__((aligned(16))) unsigned short h1s[kB][kH + 8];
    __shared__ __attribute__((aligned(16))) unsigned short h2s[kB][kH + 8];
    __shared__ float part[3][3][4][16][16];   // [m][g][kh][b][j]

    const int tid   = threadIdx.x;     // 0..767
    const int lane  = tid & 63;
    const int wid   = tid >> 6;        // 0..11
    const int jbase = blockIdx.x * 16;

    const bool zeroA = (k == 0);
    const bool zeroB = (k <= 1);

    // ---- stage h1_{k-1}, h2_{k-2} -> bf16 LDS (4096 8-elt chunks) ----
    for (int c = tid; c < 4096; c += 768) {
        const int buf = c >> 11;             // 0: h1, 1: h2
        const int b   = (c >> 7) & 15;
        const int ko  = (c & 127) * 8;
        uint4 o = {0u, 0u, 0u, 0u};
        const bool zz = buf ? zeroB : zeroA;
        if (!zz) {
            const float* src = (buf ? h2prev : h1prev) + (long)b * kH + ko;
            o = pack8(*(const float4*)(src), *(const float4*)(src + 4));
        }
        if (buf == 0) *(uint4*)&h1s[b][ko] = o;
        else          *(uint4*)&h2s[b][ko] = o;
    }
    __syncthreads();

    // ---- per-wave MFMA chains ----
    {
        const int m  = wid >> 2;       // 0..2
        const int kh = wid & 3;        // 0..3
        const unsigned short* Wm = (m == 0) ? w0 : (m == 1) ? w1 : w2;
        const unsigned short* abase =
            ((m < 2) ? &h1s[0][0] : &h2s[0][0]) + (lane & 15) * (kH + 8) + kh * 256 + (lane >> 4) * 8;
        const long woff = (long)(jbase + (lane & 15)) * kH + kh * 256 + (lane >> 4) * 8;

        floatx4 acc[3];
        #pragma unroll
        for (int g = 0; g < 3; ++g) acc[g] = (floatx4){0.f, 0.f, 0.f, 0.f};

        #pragma unroll
        for (int s = 0; s < 8; ++s) {
            const bf16x8 a = *(const bf16x8*)(abase + s * 32);
            #pragma unroll
            for (int g = 0; g < 3; ++g) {
                const bf16x8 bf = *(const bf16x8*)(Wm + (long)g * kH * kH + woff + s * 32);
                acc[g] = __builtin_amdgcn_mfma_f32_16x16x32_bf16(a, bf, acc[g], 0, 0, 0);
            }
        }
        const int aq = lane >> 4, al = lane & 15;
        #pragma unroll
        for (int g = 0; g < 3; ++g)
            #pragma unroll
            for (int r = 0; r < 4; ++r)
                part[m][g][kh][aq * 4 + r][al] = acc[g][r];
    }
    __syncthreads();

    // ---- cell updates (256 threads: b = tid>>4, j = tid&15) ----
    if (tid < 256) {
        const int b  = tid >> 4;
        const int jj = tid & 15;
        const int jg = jbase + jj;

        float gh[3][3];
        #pragma unroll
        for (int m = 0; m < 3; ++m)
            #pragma unroll
            for (int g = 0; g < 3; ++g)
                gh[m][g] = part[m][g][0][b][jj] + part[m][g][1][b][jj]
                         + part[m][g][2][b][jj] + part[m][g][3][b][jj];

        if (k < kT) {   // layer0 step t=k
            const float* gxrow = gx0_t + (long)b * (kT * 3 * kH);
            const float xr = gxrow[jg];
            const float xz = gxrow[kH + jg];
            const float xn = gxrow[2 * kH + jg];
            const float hr = gh[0][0] + bb0[jg];
            const float hz = gh[0][1] + bb0[kH + jg];
            const float hn = gh[0][2] + bb0[2 * kH + jg];
            const float hp = (k == 0) ? 0.f : h1prev[(long)b * kH + jg];
            const float r = 1.f / (1.f + __expf(-(xr + hr)));
            const float z = 1.f / (1.f + __expf(-(xz + hz)));
            const float n = tanhf(xn + r * hn);
            h1out[(long)b * kH + jg] = (1.f - z) * n + z * hp;
        }
        if (k > 0) {    // layer1 step t=k-1; gx1 = gh[1] + b_ih1
            const float xr = gh[1][0] + bb1[jg];
            const float xz = gh[1][1] + bb1[kH + jg];
            const float xn = gh[1][2] + bb1[2 * kH + jg];
            const float hr = gh[2][0] + bb2[jg];
            const float hz = gh[2][1] + bb2[kH + jg];
            const float hn = gh[2][2] + bb2[2 * kH + jg];
            const float hp = zeroB ? 0.f : h2prev[(long)b * kH + jg];
            const float r = 1.f / (1.f + __expf(-(xr + hr)));
            const float z = 1.f / (1.f + __expf(-(xz + hz)));
            const float n = tanhf(xn + r * hn);
            h2out[(long)b * kH + jg] = (1.f - z) * n + z * hp;
        }
    }
}

// ---------------------------------------------------------------------------
// kernel_launch
// ---------------------------------------------------------------------------
extern "C" void kernel_launch(void* const* d_in, const int* in_sizes, int n_in,
                              void* d_out, int out_size, void* d_ws, size_t ws_size,
                              hipStream_t stream)
{
    const float* x        = (const float*)d_in[0];   // [16,64,4096]
    const float* w_ih_l0  = (const float*)d_in[1];   // [3072,4096]
    const float* w_hh_l0  = (const float*)d_in[2];   // [3072,1024]
    const float* b_ih_l0  = (const float*)d_in[3];   // [3072]
    const float* b_hh_l0  = (const float*)d_in[4];   // [3072]
    const float* w_ih_l1  = (const float*)d_in[5];   // [3072,1024]
    const float* w_hh_l1  = (const float*)d_in[6];   // [3072,1024]
    const float* b_ih_l1  = (const float*)d_in[7];   // [3072]
    const float* b_hh_l1  = (const float*)d_in[8];   // [3072]
    const float* dec_w    = (const float*)d_in[9];   // [4096,1024]
    const float* dec_b    = (const float*)d_in[10];  // [4096]
    float* out = (float*)d_out;                      // [16,4096]

    // Workspace (~30.6 MB): gx0 12 MB + 4 h-bufs 256 KB + 3 bf16 matrices 18 MB
    float* ws    = (float*)d_ws;
    float* gx0   = ws;                                  // [1024,3072] rows b*T+t
    float* h1b0  = gx0 + (size_t)1024 * 3072;           // h1 ping-pong [16,1024]
    float* h1b1  = h1b0 + (size_t)kB * kH;
    float* h2b0  = h1b1 + (size_t)kB * kH;              // h2 ping-pong
    float* h2b1  = h2b0 + (size_t)kB * kH;
    unsigned short* wbf0 = (unsigned short*)(h2b1 + (size_t)kB * kH);
    unsigned short* wbf1 = wbf0 + (size_t)3 * kH * kH;
    unsigned short* wbf2 = wbf1 + (size_t)3 * kH * kH;
    float* h1buf[2] = {h1b0, h1b1};
    float* h2buf[2] = {h2b0, h2b1};

    const int wn4 = 3 * kH * kH / 4;

    // Pack recurrence weights fp32 -> bf16 (RNE)
    pack_bf16<<<(wn4 + 255) / 256, 256, 0, stream>>>(w_hh_l0, wbf0, wn4);
    pack_bf16<<<(wn4 + 255) / 256, 256, 0, stream>>>(w_ih_l1, wbf1, wn4);
    pack_bf16<<<(wn4 + 255) / 256, 256, 0, stream>>>(w_hh_l1, wbf2, wn4);

    // Phase A (MFMA bf16): gx0 = x @ w_ih_l0^T + b_ih_l0  (M=1024,N=3072,K=4096)
    gemm_mfma_a<<<dim3(3072 / 128, 1024 / 64), 256, 0, stream>>>(
        x, w_ih_l0, b_ih_l0, gx0, 1024, 3072, 4096);

    // Fused pipelined recurrence: 65 launches.
    // h1_t lives in h1buf[t&1]; h2_t in h2buf[t&1].
    for (int k = 0; k <= kT; ++k) {
        const float* gx0_t  = gx0 + (size_t)(k < kT ? k : 0) * 3 * kH;
        const float* h1p = h1buf[(k + 1) & 1];   // h1_{k-1}
        float*       h1o = h1buf[k & 1];         // h1_k
        const float* h2p = h2buf[k & 1];         // h2_{k-2}
        float*       h2o = h2buf[(k + 1) & 1];   // h2_{k-1}
        fused_mfma_step<<<64, 768, 0, stream>>>(
            gx0_t, wbf0, b_hh_l0, wbf1, b_ih_l1, wbf2, b_hh_l1,
            h1p, h1o, h2p, h2o, k);
    }

    // Final h2 (t=63) is in h2buf[1].
    // Decoder (fp32): out = h2_last @ dec_w^T + dec_b  (M=16,N=4096,K=1024)
    gemm_nt_bias<<<dim3(4096 / GBN, 1), 256, 0, stream>>>(
        h2buf[1], dec_w, dec_b, out, kB, 4096, 1024);
}